// Round 14
// baseline (810.225 us; speedup 1.0000x reference)
//
#include <hip/hip_runtime.h>

#define F 128
#define SPAD 136      // LDS stride (ushorts) for gather S tile
#define NR 32         // rows per tile
#define CH 112        // edges staged per chunk (112*272B = 30.5KB LDS)
#define EPW 28        // edges issued per wave per chunk (CH/4)
#define GPAD 136      // staging row stride in ushorts (272B, 16B-aligned)

typedef __attribute__((ext_vector_type(8))) short short8;
typedef __attribute__((ext_vector_type(16))) float f32x16;
typedef unsigned long long ull;
typedef __attribute__((address_space(1))) const unsigned GU;
typedef __attribute__((address_space(3))) unsigned LU;

__device__ __forceinline__ float elu_f(float x) {
    return x > 0.f ? x : __expf(x) - 1.f;
}
__device__ __forceinline__ ushort f2bf(float x) {   // fp32 -> bf16 RNE
    unsigned u = __float_as_uint(x);
    u = (u + 0x7FFFu + ((u >> 16) & 1u)) >> 16;
    return (ushort)u;
}
__device__ __forceinline__ float bf2f(ushort u) {
    return __uint_as_float((unsigned)u << 16);
}
__device__ __forceinline__ void bfma8(float* a, float v, short8 u) {
#pragma unroll
    for (int i = 0; i < 8; ++i) a[i] += v * bf2f((ushort)u[i]);
}

// ---------------- fused setup + conv1 ----------------
// blocks 0..87: weight pack; 88..272: rowptr; 273: denom+ACC zero; 274..8465: conv1
struct SetupArgs {
    const float* ws0; const float* ws1; const float* ws2; const float* ws3;
    ushort* wd0; ushort* wd1; ushort* wd2; ushort* wd3;
    const int* rows0; const int* rows1; const int* rows2; const int* rows3; const int* rows4;
    int* rp0; int* rp1; int* rp2; int* rp3; int* rp4;
    const float* mask; float* den; float* acc;   // acc: 14*8*128 floats
    const float* in; const float* Wg; const float* bg; const float* Wl; const float* bl;
    float* og; ushort* eg; float* ol; ushort* el;
};

__global__ __launch_bounds__(256) void setup_conv1(SetupArgs s) {
    __shared__ ushort tile[16384];
    int b = blockIdx.x, t = threadIdx.x;
    if (b >= 274) {
        int id = (b - 274) * 256 + t;
        int r = id >> 7, c = id & 127;
        float x0 = s.in[r * 3 + 0], x1 = s.in[r * 3 + 1], x2 = s.in[r * 3 + 2];
        float g = x0 * s.Wg[c] + x1 * s.Wg[F + c] + x2 * s.Wg[2 * F + c] + s.bg[c];
        float lo = x0 * s.Wl[c] + x1 * s.Wl[F + c] + x2 * s.Wl[2 * F + c] + s.bl[c];
        s.og[id] = g;  s.eg[id] = f2bf(elu_f(g));
        s.ol[id] = lo; s.el[id] = f2bf(elu_f(lo));
    } else if (b < 88) {
        const float* src; ushort* dst; int lb;
        if (b < 12)      { src = s.ws0; dst = s.wd0; lb = b; }
        else if (b < 16) { src = s.ws1; dst = s.wd1; lb = b - 12; }
        else if (b < 28) { src = s.ws2; dst = s.wd2; lb = b - 16; }
        else             { src = s.ws3; dst = s.wd3; lb = b - 28; }
        src += (size_t)lb * 16384; dst += (size_t)lb * 16384;
        for (int idx = t; idx < 16384; idx += 256) {
            int k = idx >> 7, nn = idx & 127;
            int k0 = k >> 4, rk = k & 15, j = rk & 7, lh = rk >> 3;
            int n0 = nn >> 5, ll = nn & 31;
            tile[((k0 * 4 + n0) * 64 + lh * 32 + ll) * 8 + j] = f2bf(src[idx]);
        }
        __syncthreads();
        ull* td = (ull*)dst; const ull* ts = (const ull*)tile;
        for (int i = t; i < 4096; i += 256) td[i] = ts[i];
    } else if (b < 273) {
        int tid = (b - 88) * 256 + t;
        const int ns[5] = {2048, 4096, 8192, 16384, 16384};
        const int es[5] = {16384, 32768, 65536, 131072, 131072};
        const int* rowsA[5] = {s.rows0, s.rows1, s.rows2, s.rows3, s.rows4};
        int* rpA[5] = {s.rp0, s.rp1, s.rp2, s.rp3, s.rp4};
        int base = 0;
        for (int lv = 0; lv < 5; ++lv) {
            int cnt = ns[lv] + 1;
            if (tid < base + cnt) {
                int r = tid - base;
                const int* rows = rowsA[lv]; int e = es[lv];
                int lo = 0, hi = e;
                while (lo < hi) { int mid = (lo + hi) >> 1; if (rows[mid] < r) lo = mid + 1; else hi = mid; }
                rpA[lv][r] = lo;
                return;
            }
            base += cnt;
        }
    } else {
        __shared__ float red[256];
        float ssum = 0.f;
        for (int i = t; i < 16384; i += 256) ssum += s.mask[i];
        red[t] = ssum; __syncthreads();
        for (int st = 128; st > 0; st >>= 1) { if (t < st) red[t] += red[t + st]; __syncthreads(); }
        if (t == 0) s.den[0] = red[0];
        for (int i = t; i < 14336; i += 256) s.acc[i] = 0.f;
    }
}

// ---------------- unified layer ----------------
struct LArgs {
    const ushort* EA; const float* RES; float* OUT; ushort* EAOUT;
    const int* rowptr; const int* cols; const float* vals;
    const ushort* Wp; const float* bias;
    const float* accin; const float* den;    // avg mode: 8-replica ACC of prev slot
    const float* mask; float* accout;        // 8-replica out
    float* EO; ushort* EE; const float* SKIP;
    int epi;  // 0 none, 1 maxpool2, 2 repeat2+skip
    int fin;  // final-head epilogue
    const float* Finp; const ushort* FEB0;
    const float* FgW2; const float* Fgb2; const float* FlW2; const float* Flb2;
    float* Fout;
};

__device__ __forceinline__ void layer_body(const LArgs& a, int blk, ushort* SS,
                                           float* FS, ushort* STG) {
    const int t = threadIdx.x;
    const int rbase = blk * NR;
    const int w = t >> 6, l = t & 63, m = l & 31, kh = l >> 5;
    const int col = w * 32 + m;
    const bool lap = (a.rowptr != nullptr);
    const bool avg = (a.accin != nullptr);

    // dense-half A-fragments straight from EA global (frag-exact layout)
    short8 afrag[8];
    {
        const ushort* ear = a.EA + (size_t)(rbase + m) * F + kh * 8;
#pragma unroll
        for (int ki = 0; ki < 8; ++ki) afrag[ki] = *(const short8*)(ear + ki * 16);
    }

    if (lap) {
        // async-staged gather: CSR edges of this tile are contiguous
        // [rp[rbase], rp[rbase+NR]); stage CH edges' EA rows into LDS via
        // global_load_lds (no dest regs -> ~112 loads in flight per block),
        // then accumulate from LDS.
        const int grp = t >> 3, l8 = t & 7;
        const int lane = t & 63;
        int row = rbase + grp;
        int re0 = a.rowptr[row], re1 = a.rowptr[row + 1];
        int b0 = a.rowptr[rbase];
        int b1 = a.rowptr[rbase + NR];
        float acc0[16];
#pragma unroll
        for (int i = 0; i < 16; ++i) acc0[i] = 0.f;

        for (int cs = b0; cs < b1; cs += CH) {
            int ce = cs + CH; if (ce > b1) ce = b1;
            int cnt = ce - cs;
            int wbeg = w * EPW;
            int wcnt = cnt - wbeg;
            if (wcnt > EPW) wcnt = EPW;
            if (wcnt < 0) wcnt = 0;
            int colv = 0;
            if (lane < wcnt) colv = a.cols[cs + wbeg + lane];
            for (int j = 0; j < wcnt; ++j) {
                int c = __shfl(colv, j, 64);
                __builtin_amdgcn_global_load_lds(
                    (GU*)(a.EA + (size_t)c * F) + lane,
                    (LU*)&STG[(wbeg + j) * GPAD], 4, 0, 0);
            }
            __builtin_amdgcn_s_waitcnt(0);
            __syncthreads();
            int ae = re0 > cs ? re0 : cs;
            int be = re1 < ce ? re1 : ce;
            for (int e = ae; e < be; ++e) {
                float v = a.vals[e];
                const ushort* lr = &STG[(e - cs) * GPAD + l8 * 16];
                short8 ua = *(const short8*)(lr);
                short8 ub = *(const short8*)(lr + 8);
                bfma8(acc0, v, ua); bfma8(acc0 + 8, v, ub);
            }
            __syncthreads();
        }
        short8 s0, s1;
#pragma unroll
        for (int i = 0; i < 8; ++i) {
            s0[i] = (short)f2bf(acc0[i]);
            s1[i] = (short)f2bf(acc0[8 + i]);
        }
        *(short8*)(&SS[grp * SPAD + l8 * 16]) = s0;
        *(short8*)(&SS[grp * SPAD + l8 * 16 + 8]) = s1;
        __syncthreads();
    } else if (avg) {
        // avg vector (8-replica sum / denom) as a broadcast bf16 A-row in LDS
        if (t < 128) {
            float s = 0.f;
#pragma unroll
            for (int r = 0; r < 8; ++r) s += a.accin[r * 128 + t];
            SS[t] = f2bf(s / a.den[0]);
        }
        __syncthreads();
    }

    f32x16 acc;
#pragma unroll
    for (int i = 0; i < 16; ++i) acc[i] = 0.f;
#pragma unroll
    for (int ki = 0; ki < 8; ++ki) {
        short8 b = *(const short8*)(a.Wp + (size_t)(((ki * 4 + w) * 64 + l) * 8));
        acc = __builtin_amdgcn_mfma_f32_32x32x16_bf16(afrag[ki], b, acc, 0, 0, 0);
    }
    if (lap || avg) {
        const ushort* esr = lap ? &SS[m * SPAD + kh * 8] : &SS[kh * 8];
#pragma unroll
        for (int ki = 0; ki < 8; ++ki) {
            short8 aa = *(const short8*)(esr + ki * 16);
            short8 b = *(const short8*)(a.Wp + 16384 + (size_t)(((ki * 4 + w) * 64 + l) * 8));
            acc = __builtin_amdgcn_mfma_f32_32x32x16_bf16(aa, b, acc, 0, 0, 0);
        }
    }

    const float bv = a.bias[col];
    float outv[16];
#pragma unroll
    for (int reg = 0; reg < 16; ++reg) {
        int r = (reg & 3) + 8 * (reg >> 2) + 4 * kh;
        size_t rg = (size_t)(rbase + r);
        float v = acc[reg] + bv;
        if (a.RES) v += a.RES[rg * F + col];
        outv[reg] = v;
        if (a.OUT) a.OUT[rg * F + col] = v;
        if (a.EAOUT) a.EAOUT[rg * F + col] = f2bf(elu_f(v));
    }
    if (a.accout) {
        float p = 0.f;
#pragma unroll
        for (int reg = 0; reg < 16; ++reg) {
            int r = (reg & 3) + 8 * (reg >> 2) + 4 * kh;
            p += elu_f(outv[reg]) * a.mask[rbase + r];
        }
        p += __shfl_xor(p, 32, 64);
        if (l < 32) atomicAdd(a.accout + (blk & 7) * 128 + col, p);
    }
    if (a.epi == 1) {          // fused maxpool2 (pairs lane-local)
        int rb2 = rbase >> 1;
#pragma unroll
        for (int q = 0; q < 4; ++q)
#pragma unroll
            for (int e2 = 0; e2 < 2; ++e2) {
                float pv = fmaxf(outv[q * 4 + e2 * 2], outv[q * 4 + e2 * 2 + 1]);
                size_t idx = (size_t)(rb2 + q * 4 + kh * 2 + e2) * F + col;
                a.EO[idx] = pv;
                a.EE[idx] = f2bf(elu_f(pv));
            }
    } else if (a.epi == 2) {   // fused repeat2 + skip add
#pragma unroll
        for (int reg = 0; reg < 16; ++reg) {
            int r = (reg & 3) + 8 * (reg >> 2) + 4 * kh;
            size_t R0 = (size_t)(2 * (rbase + r)) * F + col;
            float v0 = outv[reg] + a.SKIP[R0];
            float v1 = outv[reg] + a.SKIP[R0 + F];
            a.EO[R0] = v0;     a.EO[R0 + F] = v1;
            a.EE[R0] = f2bf(elu_f(v0)); a.EE[R0 + F] = f2bf(elu_f(v1));
        }
    }
    if (a.fin) {               // fused final head
        __syncthreads();
        if (t < 64) FS[t] = 0.f;
        __syncthreads();
        const float lw = a.FlW2[col];
#pragma unroll
        for (int reg = 0; reg < 16; ++reg) {
            int r = (reg & 3) + 8 * (reg >> 2) + 4 * kh;
            atomicAdd(&FS[r], elu_f(outv[reg]) * lw);
        }
        for (int idx = t; idx < 32 * 128; idx += 256) {
            int r = idx >> 7, cc = idx & 127;
            atomicAdd(&FS[32 + r], bf2f(a.FEB0[(size_t)(rbase + r) * F + cc]) * a.FgW2[2 * cc]);
        }
        __syncthreads();
        if (t < 32) {
            int rg = rbase + t;
            float base = a.Finp[rg * 3 + 0];
            float sg = FS[32 + t] + a.Fgb2[0] + base;
            float sl = FS[t] + a.Flb2[0] + base;
            float wg = 1.f / (1.f + __expf(-sg));
            a.Fout[rg] = sg;
            a.Fout[16384 + rg] = sl;
            a.Fout[32768 + rg] = wg * sg + (1.f - wg) * sl;
        }
    }
}

__global__ __launch_bounds__(256)
void dual_layer(LArgs A, LArgs B, int nA) {
    __shared__ ushort STG[CH * GPAD];   // 30.5 KB async gather staging
    __shared__ ushort SS[NR * SPAD];
    __shared__ float FS[64];
    bool isA = (int)blockIdx.x < nA;
    const LArgs& a = isA ? A : B;
    int blk = isA ? blockIdx.x : blockIdx.x - nA;
    layer_body(a, blk, SS, FS, STG);
}

extern "C" void kernel_launch(void* const* d_in, const int* in_sizes, int n_in,
                              void* d_out, int out_size, void* d_ws, size_t ws_size,
                              hipStream_t stream) {
    (void)in_sizes; (void)n_in; (void)out_size; (void)ws_size;
    const float* inputs = (const float*)d_in[0];
    const float* mask1  = (const float*)d_in[2];
    const int*   lrows[5] = {(const int*)d_in[3], (const int*)d_in[6], (const int*)d_in[9],
                             (const int*)d_in[12], (const int*)d_in[15]};
    const int*   lcols[5] = {(const int*)d_in[4], (const int*)d_in[7], (const int*)d_in[10],
                             (const int*)d_in[13], (const int*)d_in[16]};
    const float* lvals[5] = {(const float*)d_in[5], (const float*)d_in[8], (const float*)d_in[11],
                             (const float*)d_in[14], (const float*)d_in[17]};
    const float* gW1 = (const float*)d_in[18];
    const float* gb1 = (const float*)d_in[19];
    const float* gdW = (const float*)d_in[20];
    const float* gdb = (const float*)d_in[21];
    const float* glW = (const float*)d_in[22];
    const float* glb = (const float*)d_in[23];
    const float* guW = (const float*)d_in[24];
    const float* gub = (const float*)d_in[25];
    const float* gW2 = (const float*)d_in[26];
    const float* gb2 = (const float*)d_in[27];
    const float* lW1 = (const float*)d_in[28];
    const float* lb1 = (const float*)d_in[29];
    const float* lrW = (const float*)d_in[30];
    const float* lrb = (const float*)d_in[31];
    const float* lW2 = (const float*)d_in[32];
    const float* lb2 = (const float*)d_in[33];
    float* out = (float*)d_out;

    const int N = 16384;
    const int nlev[5] = {2048, 4096, 8192, 16384, 16384};

    char* ws = (char*)d_ws;
    size_t off = 0;
    auto alloc = [&](size_t bytes) -> char* {
        char* p = ws + off;
        off = (off + bytes + 255) & ~(size_t)255;
        return p;
    };
    float* BUF0 = (float*)alloc((size_t)N * F * 4);
    float* GU2  = (float*)alloc((size_t)N * F * 4);
    float* G2   = (float*)alloc((size_t)N * F * 4);
    float* D8   = (float*)alloc((size_t)8192 * F * 4);
    float* D4   = (float*)alloc((size_t)4096 * F * 4);
    float* D2   = (float*)alloc((size_t)2048 * F * 4);
    float* LB   = (float*)alloc((size_t)N * F * 4);
    ushort* EB0 = (ushort*)alloc((size_t)N * F * 2);
    ushort* EG1 = (ushort*)alloc((size_t)N * F * 2);
    ushort* EG2 = (ushort*)alloc((size_t)N * F * 2);
    ushort* ED8 = (ushort*)alloc((size_t)8192 * F * 2);
    ushort* ED4 = (ushort*)alloc((size_t)4096 * F * 2);
    ushort* ED2 = (ushort*)alloc((size_t)2048 * F * 2);
    ushort* LE1 = (ushort*)alloc((size_t)N * F * 2);
    ushort* LE2 = (ushort*)alloc((size_t)N * F * 2);
    int* rp[5];
    for (int i = 0; i < 5; ++i) rp[i] = (int*)alloc((size_t)(nlev[i] + 1) * 4);
    float* ACC = (float*)alloc((size_t)14 * 8 * 128 * 4);   // 8 replicas per slot
    float* DEN = (float*)alloc(4);
    ushort* Pd = (ushort*)alloc((size_t)12 * 16384 * 2);
    ushort* Pl = (ushort*)alloc((size_t)4  * 16384 * 2);
    ushort* Pu = (ushort*)alloc((size_t)12 * 16384 * 2);
    ushort* Pr = (ushort*)alloc((size_t)60 * 16384 * 2);

    SetupArgs sa;
    sa.ws0 = gdW; sa.ws1 = glW; sa.ws2 = guW; sa.ws3 = lrW;
    sa.wd0 = Pd;  sa.wd1 = Pl;  sa.wd2 = Pu;  sa.wd3 = Pr;
    sa.rows0 = lrows[0]; sa.rows1 = lrows[1]; sa.rows2 = lrows[2];
    sa.rows3 = lrows[3]; sa.rows4 = lrows[4];
    sa.rp0 = rp[0]; sa.rp1 = rp[1]; sa.rp2 = rp[2]; sa.rp3 = rp[3]; sa.rp4 = rp[4];
    sa.mask = mask1; sa.den = DEN; sa.acc = ACC;
    sa.in = inputs; sa.Wg = gW1; sa.bg = gb1; sa.Wl = lW1; sa.bl = lb1;
    sa.og = BUF0; sa.eg = EB0; sa.ol = LB; sa.el = LE1;
    setup_conv1<<<274 + 8192, 256, 0, stream>>>(sa);

    const size_t PSZ = 2 * 16384;   // packed bf16 stride per sub-layer (2 halves)

    auto mkL = [&](const ushort* ea, const float* res, float* o, ushort* eao,
                   int lv, const ushort* wp, const float* bias, float* accout,
                   int epi, float* eo, ushort* ee, const float* skip,
                   const float* accin, int fin) {
        LArgs x;
        x.EA = ea; x.RES = res; x.OUT = o; x.EAOUT = eao;
        x.rowptr = (lv >= 0) ? rp[lv] : nullptr;
        x.cols = (lv >= 0) ? lcols[lv] : nullptr;
        x.vals = (lv >= 0) ? lvals[lv] : nullptr;
        x.Wp = wp; x.bias = bias;
        x.accin = accin; x.den = DEN;
        x.mask = mask1; x.accout = accout;
        x.EO = eo; x.EE = ee; x.SKIP = skip; x.epi = epi;
        x.fin = fin;
        x.Finp = inputs; x.FEB0 = EB0;
        x.FgW2 = gW2; x.Fgb2 = gb2; x.FlW2 = lW2; x.Flb2 = lb2; x.Fout = out;
        return x;
    };

    // ---- global branch slots (pool/upadd fused into sub2 epilogues) ----
    LArgs gs[14]; int gn[14];
    gs[0]  = mkL(EB0, 0, 0, EG1, 3, Pd + 0 * PSZ, gdb + 0,   0, 0, 0, 0, 0, 0, 0);  gn[0]  = 16384;
    gs[1]  = mkL(EG1, BUF0, 0, 0, 3, Pd + 1 * PSZ, gdb + 128, 0, 1, D8, ED8, 0, 0, 0); gn[1] = 16384;
    gs[2]  = mkL(ED8, 0, 0, EG1, 2, Pd + 2 * PSZ, gdb + 256, 0, 0, 0, 0, 0, 0, 0);  gn[2]  = 8192;
    gs[3]  = mkL(EG1, D8, 0, 0, 2, Pd + 3 * PSZ, gdb + 384, 0, 1, D4, ED4, 0, 0, 0); gn[3]  = 8192;
    gs[4]  = mkL(ED4, 0, 0, EG1, 1, Pd + 4 * PSZ, gdb + 512, 0, 0, 0, 0, 0, 0, 0);  gn[4]  = 4096;
    gs[5]  = mkL(EG1, D4, 0, 0, 1, Pd + 5 * PSZ, gdb + 640, 0, 1, D2, ED2, 0, 0, 0); gn[5]  = 4096;
    gs[6]  = mkL(ED2, 0, 0, EG1, 0, Pl + 0 * PSZ, glb + 0,   0, 0, 0, 0, 0, 0, 0);  gn[6]  = 2048;
    gs[7]  = mkL(EG1, D2, 0, 0, 0, Pl + 1 * PSZ, glb + 128, 0, 2, GU2, EG2, D4, 0, 0); gn[7] = 2048;
    gs[8]  = mkL(EG2, 0, 0, EG1, 1, Pu + 0 * PSZ, gub + 0,   0, 0, 0, 0, 0, 0, 0);  gn[8]  = 4096;
    gs[9]  = mkL(EG1, GU2, 0, 0, 1, Pu + 1 * PSZ, gub + 128, 0, 2, G2, EG2, D8, 0, 0); gn[9] = 4096;
    gs[10] = mkL(EG2, 0, 0, EG1, 2, Pu + 2 * PSZ, gub + 256, 0, 0, 0, 0, 0, 0, 0);  gn[10] = 8192;
    gs[11] = mkL(EG1, G2, 0, 0, 2, Pu + 3 * PSZ, gub + 384, 0, 2, GU2, EG2, BUF0, 0, 0); gn[11] = 8192;
    gs[12] = mkL(EG2, 0, 0, EG1, 3, Pu + 4 * PSZ, gub + 512, 0, 0, 0, 0, 0, 0, 0);  gn[12] = 16384;
    gs[13] = mkL(EG1, GU2, 0, EB0, 3, Pu + 5 * PSZ, gub + 640, 0, 0, 0, 0, 0, 0, 0); gn[13] = 16384;

    int gi = 0;
    auto launchLap = [&](const LArgs& loc) {
        if (gi < 14) {
            int na = gn[gi] / NR;
            dual_layer<<<na + 512, 256, 0, stream>>>(gs[gi], loc, na);
            ++gi;
        } else {
            dual_layer<<<512, 256, 0, stream>>>(loc, loc, 512);
        }
    };

    for (int i = 0; i < 15; ++i) {
        const ushort* P1 = Pr + (size_t)(2 * i) * PSZ;
        const ushort* P2 = Pr + (size_t)(2 * i + 1) * PSZ;
        const float* b1 = lrb + (size_t)i * 256;
        const float* b2 = b1 + 128;
        if ((i & 1) == 0) {   // lap block on L (level 4)
            LArgs s1 = mkL(LE1, 0, 0, LE2, 4, P1, b1, 0, 0, 0, 0, 0, 0, 0);
            float* accout = (i <= 12) ? (ACC + (size_t)i * 1024) : nullptr;
            int fin = (i == 14);
            LArgs s2 = mkL(LE2, LB, fin ? nullptr : LB, fin ? nullptr : LE1, 4,
                           P2, b2, accout, 0, 0, 0, 0, 0, fin);
            launchLap(s1);
            launchLap(s2);
        } else {              // avg block: MFMA-based rank-1 fold (broadcast avg row)
            LArgs s1 = mkL(LE1, 0, 0, LE2, -1, P1, b1, ACC + (size_t)i * 1024,
                           0, 0, 0, 0, ACC + (size_t)(i - 1) * 1024, 0);
            LArgs s2 = mkL(LE2, LB, LB, LE1, -1, P2, b2, 0,
                           0, 0, 0, 0, ACC + (size_t)i * 1024, 0);
            launchLap(s1);
            launchLap(s2);
        }
    }
}

// Round 15
// 678.532 us; speedup vs baseline: 1.1941x; 1.1941x over previous
//
#include <hip/hip_runtime.h>

#define F 128
#define SPAD 136      // LDS stride (ushorts) for gather S tile
#define NR 32         // rows per tile

typedef __attribute__((ext_vector_type(8))) short short8;
typedef __attribute__((ext_vector_type(16))) float f32x16;
typedef unsigned long long ull;

__device__ __forceinline__ float elu_f(float x) {
    return x > 0.f ? x : __expf(x) - 1.f;
}
__device__ __forceinline__ ushort f2bf(float x) {   // fp32 -> bf16 RNE
    unsigned u = __float_as_uint(x);
    u = (u + 0x7FFFu + ((u >> 16) & 1u)) >> 16;
    return (ushort)u;
}
__device__ __forceinline__ float bf2f(ushort u) {
    return __uint_as_float((unsigned)u << 16);
}
__device__ __forceinline__ void bfma8(float* a, float v, short8 u) {
#pragma unroll
    for (int i = 0; i < 8; ++i) a[i] += v * bf2f((ushort)u[i]);
}

// ---------------- fused setup + conv1 ----------------
// blocks 0..87: weight pack; 88..272: rowptr; 273: denom+ACC zero; 274..8465: conv1
struct SetupArgs {
    const float* ws0; const float* ws1; const float* ws2; const float* ws3;
    ushort* wd0; ushort* wd1; ushort* wd2; ushort* wd3;
    const int* rows0; const int* rows1; const int* rows2; const int* rows3; const int* rows4;
    int* rp0; int* rp1; int* rp2; int* rp3; int* rp4;
    const float* mask; float* den; float* acc;   // acc: 14*8*128 floats
    const float* in; const float* Wg; const float* bg; const float* Wl; const float* bl;
    float* og; ushort* eg; float* ol; ushort* el;
};

__global__ __launch_bounds__(256) void setup_conv1(SetupArgs s) {
    __shared__ ushort tile[16384];
    int b = blockIdx.x, t = threadIdx.x;
    if (b >= 274) {
        int id = (b - 274) * 256 + t;
        int r = id >> 7, c = id & 127;
        float x0 = s.in[r * 3 + 0], x1 = s.in[r * 3 + 1], x2 = s.in[r * 3 + 2];
        float g = x0 * s.Wg[c] + x1 * s.Wg[F + c] + x2 * s.Wg[2 * F + c] + s.bg[c];
        float lo = x0 * s.Wl[c] + x1 * s.Wl[F + c] + x2 * s.Wl[2 * F + c] + s.bl[c];
        s.og[id] = g;  s.eg[id] = f2bf(elu_f(g));
        s.ol[id] = lo; s.el[id] = f2bf(elu_f(lo));
    } else if (b < 88) {
        const float* src; ushort* dst; int lb;
        if (b < 12)      { src = s.ws0; dst = s.wd0; lb = b; }
        else if (b < 16) { src = s.ws1; dst = s.wd1; lb = b - 12; }
        else if (b < 28) { src = s.ws2; dst = s.wd2; lb = b - 16; }
        else             { src = s.ws3; dst = s.wd3; lb = b - 28; }
        src += (size_t)lb * 16384; dst += (size_t)lb * 16384;
        for (int idx = t; idx < 16384; idx += 256) {
            int k = idx >> 7, nn = idx & 127;
            int k0 = k >> 4, rk = k & 15, j = rk & 7, lh = rk >> 3;
            int n0 = nn >> 5, ll = nn & 31;
            tile[((k0 * 4 + n0) * 64 + lh * 32 + ll) * 8 + j] = f2bf(src[idx]);
        }
        __syncthreads();
        ull* td = (ull*)dst; const ull* ts = (const ull*)tile;
        for (int i = t; i < 4096; i += 256) td[i] = ts[i];
    } else if (b < 273) {
        int tid = (b - 88) * 256 + t;
        const int ns[5] = {2048, 4096, 8192, 16384, 16384};
        const int es[5] = {16384, 32768, 65536, 131072, 131072};
        const int* rowsA[5] = {s.rows0, s.rows1, s.rows2, s.rows3, s.rows4};
        int* rpA[5] = {s.rp0, s.rp1, s.rp2, s.rp3, s.rp4};
        int base = 0;
        for (int lv = 0; lv < 5; ++lv) {
            int cnt = ns[lv] + 1;
            if (tid < base + cnt) {
                int r = tid - base;
                const int* rows = rowsA[lv]; int e = es[lv];
                int lo = 0, hi = e;
                while (lo < hi) { int mid = (lo + hi) >> 1; if (rows[mid] < r) lo = mid + 1; else hi = mid; }
                rpA[lv][r] = lo;
                return;
            }
            base += cnt;
        }
    } else {
        __shared__ float red[256];
        float ssum = 0.f;
        for (int i = t; i < 16384; i += 256) ssum += s.mask[i];
        red[t] = ssum; __syncthreads();
        for (int st = 128; st > 0; st >>= 1) { if (t < st) red[t] += red[t + st]; __syncthreads(); }
        if (t == 0) s.den[0] = red[0];
        for (int i = t; i < 14336; i += 256) s.acc[i] = 0.f;
    }
}

// ---------------- unified layer ----------------
struct LArgs {
    const ushort* EA; const float* RES; float* OUT; ushort* EAOUT;
    const int* rowptr; const int* cols; const float* vals;
    const ushort* Wp; const float* bias;
    const float* accin; const float* den;    // avg mode: 8-replica ACC of prev slot
    const float* mask; float* accout;        // 8-replica out
    float* EO; ushort* EE; const float* SKIP;
    int epi;  // 0 none, 1 maxpool2, 2 repeat2+skip
    int fin;  // final-head epilogue
    const float* Finp; const ushort* FEB0;
    const float* FgW2; const float* Fgb2; const float* FlW2; const float* Flb2;
    float* Fout;
};

__device__ __forceinline__ void layer_body(const LArgs& a, int blk, ushort* SS, float* FS) {
    const int t = threadIdx.x;
    const int rbase = blk * NR;
    const int w = t >> 6, l = t & 63, m = l & 31, kh = l >> 5;
    const int col = w * 32 + m;
    const bool lap = (a.rowptr != nullptr);
    const bool avg = (a.accin != nullptr);

    // dense-half A-fragments straight from EA global (frag-exact layout)
    short8 afrag[8];
    {
        const ushort* ear = a.EA + (size_t)(rbase + m) * F + kh * 8;
#pragma unroll
        for (int ki = 0; ki < 8; ++ki) afrag[ki] = *(const short8*)(ear + ki * 16);
    }

    if (lap) {
        // one row per 8-lane group (32 concurrent rows/block), x4 edge unroll
        const int grp = t >> 3, l8 = t & 7;
        const short8* EA8 = (const short8*)a.EA;
        const int chunk = l8 * 2;
        int row = rbase + grp;
        int e0 = a.rowptr[row], e1 = a.rowptr[row + 1];
        float acc0[16], acc1[16];
#pragma unroll
        for (int i = 0; i < 16; ++i) { acc0[i] = 0.f; acc1[i] = 0.f; }
        int e = e0;
        for (; e + 4 <= e1; e += 4) {
            int c0 = a.cols[e + 0], c1 = a.cols[e + 1], c2 = a.cols[e + 2], c3 = a.cols[e + 3];
            float v0 = a.vals[e + 0], v1 = a.vals[e + 1], v2 = a.vals[e + 2], v3 = a.vals[e + 3];
            short8 u0a = EA8[(size_t)c0 * 16 + chunk], u0b = EA8[(size_t)c0 * 16 + chunk + 1];
            short8 u1a = EA8[(size_t)c1 * 16 + chunk], u1b = EA8[(size_t)c1 * 16 + chunk + 1];
            short8 u2a = EA8[(size_t)c2 * 16 + chunk], u2b = EA8[(size_t)c2 * 16 + chunk + 1];
            short8 u3a = EA8[(size_t)c3 * 16 + chunk], u3b = EA8[(size_t)c3 * 16 + chunk + 1];
            bfma8(acc0, v0, u0a); bfma8(acc0 + 8, v0, u0b);
            bfma8(acc1, v1, u1a); bfma8(acc1 + 8, v1, u1b);
            bfma8(acc0, v2, u2a); bfma8(acc0 + 8, v2, u2b);
            bfma8(acc1, v3, u3a); bfma8(acc1 + 8, v3, u3b);
        }
        for (; e < e1; ++e) {
            int cc = a.cols[e];
            float v = a.vals[e];
            short8 ua = EA8[(size_t)cc * 16 + chunk], ub = EA8[(size_t)cc * 16 + chunk + 1];
            bfma8(acc0, v, ua); bfma8(acc0 + 8, v, ub);
        }
        short8 s0, s1;
#pragma unroll
        for (int i = 0; i < 8; ++i) {
            s0[i] = (short)f2bf(acc0[i] + acc1[i]);
            s1[i] = (short)f2bf(acc0[8 + i] + acc1[8 + i]);
        }
        *(short8*)(&SS[grp * SPAD + l8 * 16]) = s0;
        *(short8*)(&SS[grp * SPAD + l8 * 16 + 8]) = s1;
        __syncthreads();
    } else if (avg) {
        // avg vector (8-replica sum / denom) as a broadcast bf16 A-row in LDS
        if (t < 128) {
            float s = 0.f;
#pragma unroll
            for (int r = 0; r < 8; ++r) s += a.accin[r * 128 + t];
            SS[t] = f2bf(s / a.den[0]);
        }
        __syncthreads();
    }

    f32x16 acc;
#pragma unroll
    for (int i = 0; i < 16; ++i) acc[i] = 0.f;
#pragma unroll
    for (int ki = 0; ki < 8; ++ki) {
        short8 b = *(const short8*)(a.Wp + (size_t)(((ki * 4 + w) * 64 + l) * 8));
        acc = __builtin_amdgcn_mfma_f32_32x32x16_bf16(afrag[ki], b, acc, 0, 0, 0);
    }
    if (lap || avg) {
        const ushort* esr = lap ? &SS[m * SPAD + kh * 8] : &SS[kh * 8];
#pragma unroll
        for (int ki = 0; ki < 8; ++ki) {
            short8 aa = *(const short8*)(esr + ki * 16);
            short8 b = *(const short8*)(a.Wp + 16384 + (size_t)(((ki * 4 + w) * 64 + l) * 8));
            acc = __builtin_amdgcn_mfma_f32_32x32x16_bf16(aa, b, acc, 0, 0, 0);
        }
    }

    const float bv = a.bias[col];
    float outv[16];
#pragma unroll
    for (int reg = 0; reg < 16; ++reg) {
        int r = (reg & 3) + 8 * (reg >> 2) + 4 * kh;
        size_t rg = (size_t)(rbase + r);
        float v = acc[reg] + bv;
        if (a.RES) v += a.RES[rg * F + col];
        outv[reg] = v;
        if (a.OUT) a.OUT[rg * F + col] = v;
        if (a.EAOUT) a.EAOUT[rg * F + col] = f2bf(elu_f(v));
    }
    if (a.accout) {
        float p = 0.f;
#pragma unroll
        for (int reg = 0; reg < 16; ++reg) {
            int r = (reg & 3) + 8 * (reg >> 2) + 4 * kh;
            p += elu_f(outv[reg]) * a.mask[rbase + r];
        }
        p += __shfl_xor(p, 32, 64);
        if (l < 32) atomicAdd(a.accout + (blk & 7) * 128 + col, p);
    }
    if (a.epi == 1) {          // fused maxpool2 (pairs lane-local)
        int rb2 = rbase >> 1;
#pragma unroll
        for (int q = 0; q < 4; ++q)
#pragma unroll
            for (int e2 = 0; e2 < 2; ++e2) {
                float pv = fmaxf(outv[q * 4 + e2 * 2], outv[q * 4 + e2 * 2 + 1]);
                size_t idx = (size_t)(rb2 + q * 4 + kh * 2 + e2) * F + col;
                a.EO[idx] = pv;
                a.EE[idx] = f2bf(elu_f(pv));
            }
    } else if (a.epi == 2) {   // fused repeat2 + skip add
#pragma unroll
        for (int reg = 0; reg < 16; ++reg) {
            int r = (reg & 3) + 8 * (reg >> 2) + 4 * kh;
            size_t R0 = (size_t)(2 * (rbase + r)) * F + col;
            float v0 = outv[reg] + a.SKIP[R0];
            float v1 = outv[reg] + a.SKIP[R0 + F];
            a.EO[R0] = v0;     a.EO[R0 + F] = v1;
            a.EE[R0] = f2bf(elu_f(v0)); a.EE[R0 + F] = f2bf(elu_f(v1));
        }
    }
    if (a.fin) {               // fused final head
        __syncthreads();
        if (t < 64) FS[t] = 0.f;
        __syncthreads();
        const float lw = a.FlW2[col];
#pragma unroll
        for (int reg = 0; reg < 16; ++reg) {
            int r = (reg & 3) + 8 * (reg >> 2) + 4 * kh;
            atomicAdd(&FS[r], elu_f(outv[reg]) * lw);
        }
        for (int idx = t; idx < 32 * 128; idx += 256) {
            int r = idx >> 7, cc = idx & 127;
            atomicAdd(&FS[32 + r], bf2f(a.FEB0[(size_t)(rbase + r) * F + cc]) * a.FgW2[2 * cc]);
        }
        __syncthreads();
        if (t < 32) {
            int rg = rbase + t;
            float base = a.Finp[rg * 3 + 0];
            float sg = FS[32 + t] + a.Fgb2[0] + base;
            float sl = FS[t] + a.Flb2[0] + base;
            float wg = 1.f / (1.f + __expf(-sg));
            a.Fout[rg] = sg;
            a.Fout[16384 + rg] = sl;
            a.Fout[32768 + rg] = wg * sg + (1.f - wg) * sl;
        }
    }
}

__global__ __launch_bounds__(256)
void dual_layer(LArgs A, LArgs B, int nA) {
    __shared__ ushort SS[NR * SPAD];
    __shared__ float FS[64];
    bool isA = (int)blockIdx.x < nA;
    const LArgs& a = isA ? A : B;
    int blk = isA ? blockIdx.x : blockIdx.x - nA;
    layer_body(a, blk, SS, FS);
}

extern "C" void kernel_launch(void* const* d_in, const int* in_sizes, int n_in,
                              void* d_out, int out_size, void* d_ws, size_t ws_size,
                              hipStream_t stream) {
    (void)in_sizes; (void)n_in; (void)out_size; (void)ws_size;
    const float* inputs = (const float*)d_in[0];
    const float* mask1  = (const float*)d_in[2];
    const int*   lrows[5] = {(const int*)d_in[3], (const int*)d_in[6], (const int*)d_in[9],
                             (const int*)d_in[12], (const int*)d_in[15]};
    const int*   lcols[5] = {(const int*)d_in[4], (const int*)d_in[7], (const int*)d_in[10],
                             (const int*)d_in[13], (const int*)d_in[16]};
    const float* lvals[5] = {(const float*)d_in[5], (const float*)d_in[8], (const float*)d_in[11],
                             (const float*)d_in[14], (const float*)d_in[17]};
    const float* gW1 = (const float*)d_in[18];
    const float* gb1 = (const float*)d_in[19];
    const float* gdW = (const float*)d_in[20];
    const float* gdb = (const float*)d_in[21];
    const float* glW = (const float*)d_in[22];
    const float* glb = (const float*)d_in[23];
    const float* guW = (const float*)d_in[24];
    const float* gub = (const float*)d_in[25];
    const float* gW2 = (const float*)d_in[26];
    const float* gb2 = (const float*)d_in[27];
    const float* lW1 = (const float*)d_in[28];
    const float* lb1 = (const float*)d_in[29];
    const float* lrW = (const float*)d_in[30];
    const float* lrb = (const float*)d_in[31];
    const float* lW2 = (const float*)d_in[32];
    const float* lb2 = (const float*)d_in[33];
    float* out = (float*)d_out;

    const int N = 16384;
    const int nlev[5] = {2048, 4096, 8192, 16384, 16384};

    char* ws = (char*)d_ws;
    size_t off = 0;
    auto alloc = [&](size_t bytes) -> char* {
        char* p = ws + off;
        off = (off + bytes + 255) & ~(size_t)255;
        return p;
    };
    float* BUF0 = (float*)alloc((size_t)N * F * 4);
    float* GU2  = (float*)alloc((size_t)N * F * 4);
    float* G2   = (float*)alloc((size_t)N * F * 4);
    float* D8   = (float*)alloc((size_t)8192 * F * 4);
    float* D4   = (float*)alloc((size_t)4096 * F * 4);
    float* D2   = (float*)alloc((size_t)2048 * F * 4);
    float* LB   = (float*)alloc((size_t)N * F * 4);
    ushort* EB0 = (ushort*)alloc((size_t)N * F * 2);
    ushort* EG1 = (ushort*)alloc((size_t)N * F * 2);
    ushort* EG2 = (ushort*)alloc((size_t)N * F * 2);
    ushort* ED8 = (ushort*)alloc((size_t)8192 * F * 2);
    ushort* ED4 = (ushort*)alloc((size_t)4096 * F * 2);
    ushort* ED2 = (ushort*)alloc((size_t)2048 * F * 2);
    ushort* LE1 = (ushort*)alloc((size_t)N * F * 2);
    ushort* LE2 = (ushort*)alloc((size_t)N * F * 2);
    int* rp[5];
    for (int i = 0; i < 5; ++i) rp[i] = (int*)alloc((size_t)(nlev[i] + 1) * 4);
    float* ACC = (float*)alloc((size_t)14 * 8 * 128 * 4);   // 8 replicas per slot
    float* DEN = (float*)alloc(4);
    ushort* Pd = (ushort*)alloc((size_t)12 * 16384 * 2);
    ushort* Pl = (ushort*)alloc((size_t)4  * 16384 * 2);
    ushort* Pu = (ushort*)alloc((size_t)12 * 16384 * 2);
    ushort* Pr = (ushort*)alloc((size_t)60 * 16384 * 2);

    SetupArgs sa;
    sa.ws0 = gdW; sa.ws1 = glW; sa.ws2 = guW; sa.ws3 = lrW;
    sa.wd0 = Pd;  sa.wd1 = Pl;  sa.wd2 = Pu;  sa.wd3 = Pr;
    sa.rows0 = lrows[0]; sa.rows1 = lrows[1]; sa.rows2 = lrows[2];
    sa.rows3 = lrows[3]; sa.rows4 = lrows[4];
    sa.rp0 = rp[0]; sa.rp1 = rp[1]; sa.rp2 = rp[2]; sa.rp3 = rp[3]; sa.rp4 = rp[4];
    sa.mask = mask1; sa.den = DEN; sa.acc = ACC;
    sa.in = inputs; sa.Wg = gW1; sa.bg = gb1; sa.Wl = lW1; sa.bl = lb1;
    sa.og = BUF0; sa.eg = EB0; sa.ol = LB; sa.el = LE1;
    setup_conv1<<<274 + 8192, 256, 0, stream>>>(sa);

    const size_t PSZ = 2 * 16384;   // packed bf16 stride per sub-layer (2 halves)

    auto mkL = [&](const ushort* ea, const float* res, float* o, ushort* eao,
                   int lv, const ushort* wp, const float* bias, float* accout,
                   int epi, float* eo, ushort* ee, const float* skip,
                   const float* accin, int fin) {
        LArgs x;
        x.EA = ea; x.RES = res; x.OUT = o; x.EAOUT = eao;
        x.rowptr = (lv >= 0) ? rp[lv] : nullptr;
        x.cols = (lv >= 0) ? lcols[lv] : nullptr;
        x.vals = (lv >= 0) ? lvals[lv] : nullptr;
        x.Wp = wp; x.bias = bias;
        x.accin = accin; x.den = DEN;
        x.mask = mask1; x.accout = accout;
        x.EO = eo; x.EE = ee; x.SKIP = skip; x.epi = epi;
        x.fin = fin;
        x.Finp = inputs; x.FEB0 = EB0;
        x.FgW2 = gW2; x.Fgb2 = gb2; x.FlW2 = lW2; x.Flb2 = lb2; x.Fout = out;
        return x;
    };

    // ---- global branch slots (pool/upadd fused into sub2 epilogues) ----
    LArgs gs[14]; int gn[14];
    gs[0]  = mkL(EB0, 0, 0, EG1, 3, Pd + 0 * PSZ, gdb + 0,   0, 0, 0, 0, 0, 0, 0);  gn[0]  = 16384;
    gs[1]  = mkL(EG1, BUF0, 0, 0, 3, Pd + 1 * PSZ, gdb + 128, 0, 1, D8, ED8, 0, 0, 0); gn[1] = 16384;
    gs[2]  = mkL(ED8, 0, 0, EG1, 2, Pd + 2 * PSZ, gdb + 256, 0, 0, 0, 0, 0, 0, 0);  gn[2]  = 8192;
    gs[3]  = mkL(EG1, D8, 0, 0, 2, Pd + 3 * PSZ, gdb + 384, 0, 1, D4, ED4, 0, 0, 0); gn[3]  = 8192;
    gs[4]  = mkL(ED4, 0, 0, EG1, 1, Pd + 4 * PSZ, gdb + 512, 0, 0, 0, 0, 0, 0, 0);  gn[4]  = 4096;
    gs[5]  = mkL(EG1, D4, 0, 0, 1, Pd + 5 * PSZ, gdb + 640, 0, 1, D2, ED2, 0, 0, 0); gn[5]  = 4096;
    gs[6]  = mkL(ED2, 0, 0, EG1, 0, Pl + 0 * PSZ, glb + 0,   0, 0, 0, 0, 0, 0, 0);  gn[6]  = 2048;
    gs[7]  = mkL(EG1, D2, 0, 0, 0, Pl + 1 * PSZ, glb + 128, 0, 2, GU2, EG2, D4, 0, 0); gn[7] = 2048;
    gs[8]  = mkL(EG2, 0, 0, EG1, 1, Pu + 0 * PSZ, gub + 0,   0, 0, 0, 0, 0, 0, 0);  gn[8]  = 4096;
    gs[9]  = mkL(EG1, GU2, 0, 0, 1, Pu + 1 * PSZ, gub + 128, 0, 2, G2, EG2, D8, 0, 0); gn[9] = 4096;
    gs[10] = mkL(EG2, 0, 0, EG1, 2, Pu + 2 * PSZ, gub + 256, 0, 0, 0, 0, 0, 0, 0);  gn[10] = 8192;
    gs[11] = mkL(EG1, G2, 0, 0, 2, Pu + 3 * PSZ, gub + 384, 0, 2, GU2, EG2, BUF0, 0, 0); gn[11] = 8192;
    gs[12] = mkL(EG2, 0, 0, EG1, 3, Pu + 4 * PSZ, gub + 512, 0, 0, 0, 0, 0, 0, 0);  gn[12] = 16384;
    gs[13] = mkL(EG1, GU2, 0, EB0, 3, Pu + 5 * PSZ, gub + 640, 0, 0, 0, 0, 0, 0, 0); gn[13] = 16384;

    int gi = 0;
    auto launchLap = [&](const LArgs& loc) {
        if (gi < 14) {
            int na = gn[gi] / NR;
            dual_layer<<<na + 512, 256, 0, stream>>>(gs[gi], loc, na);
            ++gi;
        } else {
            dual_layer<<<512, 256, 0, stream>>>(loc, loc, 512);
        }
    };

    for (int i = 0; i < 15; ++i) {
        const ushort* P1 = Pr + (size_t)(2 * i) * PSZ;
        const ushort* P2 = Pr + (size_t)(2 * i + 1) * PSZ;
        const float* b1 = lrb + (size_t)i * 256;
        const float* b2 = b1 + 128;
        if ((i & 1) == 0) {   // lap block on L (level 4)
            LArgs s1 = mkL(LE1, 0, 0, LE2, 4, P1, b1, 0, 0, 0, 0, 0, 0, 0);
            float* accout = (i <= 12) ? (ACC + (size_t)i * 1024) : nullptr;
            int fin = (i == 14);
            LArgs s2 = mkL(LE2, LB, fin ? nullptr : LB, fin ? nullptr : LE1, 4,
                           P2, b2, accout, 0, 0, 0, 0, 0, fin);
            launchLap(s1);
            launchLap(s2);
        } else {              // avg block: MFMA-based rank-1 fold (broadcast avg row)
            LArgs s1 = mkL(LE1, 0, 0, LE2, -1, P1, b1, ACC + (size_t)i * 1024,
                           0, 0, 0, 0, ACC + (size_t)(i - 1) * 1024, 0);
            LArgs s2 = mkL(LE2, LB, LB, LE1, -1, P2, b2, 0,
                           0, 0, 0, 0, ACC + (size_t)i * 1024, 0);
            launchLap(s1);
            launchLap(s2);
        }
    }
}